// Round 1
// 1056.215 us; speedup vs baseline: 1.0230x; 1.0230x over previous
//
#include <hip/hip_runtime.h>
#include <hip/hip_bf16.h>
#include <cstdint>
#include <cstddef>

typedef __hip_bfloat16 bf16;
typedef __attribute__((ext_vector_type(8))) short short8;   // 8 bf16 in 4 VGPRs
typedef __attribute__((ext_vector_type(4))) short short4v;
typedef __attribute__((ext_vector_type(4))) float f32x4;
#define DEVI __device__ __forceinline__

constexpr int Bb = 2, Ll = 6273, Pp = 1568, LL2 = 1569, LP = 1600;
constexpr float QK_SCALE = 0.04419417382415922f;  // 512^-0.5

DEVI short f2bs(float f) {
  __hip_bfloat16 h = __float2bfloat16(f);
  return __builtin_bit_cast(short, h);
}
DEVI float bs2f(short s) {
  __hip_bfloat16 h = __builtin_bit_cast(__hip_bfloat16, s);
  return __bfloat162float(h);
}

// async global->LDS, 16B per lane. LDS dest = wave-uniform base + lane*16.
DEVI void gload16(const short* g, short* l) {
  __builtin_amdgcn_global_load_lds(
      (const __attribute__((address_space(1))) void*)g,
      (__attribute__((address_space(3))) void*)l,
      16, 0, 0);
}

// ===========================================================================
// 128x128 MFMA tile core, BK=64, 256 threads = 4 waves in 2x2 (each 64x64 via
// 4x4 frags of mfma_f32_16x16x32_bf16). LDS 128x64 shorts per tile, 16B-slot
// XOR swizzle (slot ^= row&7) -> conflict-minimal b128 reads.
// Staging: global_load_lds with LINEAR LDS dest + inverse-swizzled per-lane
// global SOURCE (rule 21: same involution on both sides). Read side unchanged.
// C/D layout per m89: col=lane&15, row=quad*4+e.
// ===========================================================================
constexpr int BK = 64;

DEVI int sw_idx(int row, int slot) {            // slot = 16B unit (8 shorts)
  return row * BK + (((slot) ^ (row & 7)) << 3);
}

DEVI void mma128(const short* As, const short* Bs, int lane, int wr, int wc,
                 f32x4 (&acc)[4][4]) {
  int m = lane & 15, quad = lane >> 4;
  #pragma unroll
  for (int kh = 0; kh < 2; ++kh) {
    int slot = kh * 4 + quad;
    short8 a[4], b[4];
    #pragma unroll
    for (int i = 0; i < 4; ++i) {
      int row = wr * 64 + i * 16 + m;
      a[i] = *(const short8*)(As + sw_idx(row, slot));
    }
    #pragma unroll
    for (int j = 0; j < 4; ++j) {
      int row = wc * 64 + j * 16 + m;
      b[j] = *(const short8*)(Bs + sw_idx(row, slot));
    }
    #pragma unroll
    for (int i = 0; i < 4; ++i)
      #pragma unroll
      for (int j = 0; j < 4; ++j)
        acc[i][j] = __builtin_amdgcn_mfma_f32_16x16x32_bf16(a[i], b[j], acc[i][j], 0, 0, 0);
  }
}

// Old 64x64 core (kept for the small px_pool only)
constexpr int LDT = 40;
DEVI void mma_step(const short* As, const short* Bs, int lane, int wr, int wc,
                   f32x4& c00, f32x4& c01, f32x4& c10, f32x4& c11) {
  int m = lane & 15, quad = lane >> 4;
  const short* a = As + (wr * 32 + m) * LDT + quad * 8;
  const short* b = Bs + (wc * 32 + m) * LDT + quad * 8;
  short8 a0 = *(const short8*)a;
  short8 a1 = *(const short8*)(a + 16 * LDT);
  short8 b0 = *(const short8*)b;
  short8 b1 = *(const short8*)(b + 16 * LDT);
  c00 = __builtin_amdgcn_mfma_f32_16x16x32_bf16(a0, b0, c00, 0, 0, 0);
  c01 = __builtin_amdgcn_mfma_f32_16x16x32_bf16(a0, b1, c01, 0, 0, 0);
  c10 = __builtin_amdgcn_mfma_f32_16x16x32_bf16(a1, b0, c10, 0, 0, 0);
  c11 = __builtin_amdgcn_mfma_f32_16x16x32_bf16(a1, b1, c11, 0, 0, 0);
}

// ---------------------------------------------------------------------------
__global__ void emb_kernel(float* __restrict__ embz) {
  int idx = blockIdx.x * 256 + threadIdx.x;
  if (idx >= LP * 512) return;
  int p = idx >> 9, d = idx & 511;
  float v = 0.f;
  if (p > 0 && p < LL2) {
    int pb = p - 1;
    int t = pb / 196, r = pb % 196;
    int h = r / 14, ww = r % 14;
    int pos, j, half;
    if (d < 170)      { pos = t;  j = d;       half = 85; }
    else if (d < 340) { pos = h;  j = d - 170; half = 85; }
    else              { pos = ww; j = d - 340; half = 86; }
    int jj = (j < half) ? j : (j - half);
    float omega = powf(10000.f, -(float)jj / (float)half);
    float ang = (float)pos * omega;
    v = (j < half) ? sinf(ang) : cosf(ang);
  }
  embz[idx] = v;
}

// f32 -> bf16 bulk convert, 4 elements/thread
__global__ void cvt_kernel(const float* __restrict__ src, short* __restrict__ dst, int n4) {
  int idx = blockIdx.x * 256 + threadIdx.x;
  if (idx >= n4) return;
  float4 v = *(const float4*)(src + (size_t)idx * 4);
  short4v o = { f2bs(v.x), f2bs(v.y), f2bs(v.z), f2bs(v.w) };
  *(short4v*)(dst + (size_t)idx * 4) = o;
}

// wpT[n][tap*512+k] = bf16(wp[n*2048 + k*4 + tap])  (works for wpx/wpq/wpk/wpv)
__global__ void wpxt_kernel(const float* __restrict__ wp, short* __restrict__ wpT) {
  int idx = blockIdx.x * 256 + threadIdx.x;
  if (idx >= 512 * 2048) return;
  int n = idx >> 11, rem = idx & 2047, tap = rem >> 9, k = rem & 511;
  wpT[idx] = f2bs(wp[n * 2048 + k * 4 + tap]);
}

// WT[h][k][i] = bf16(W[(h*512+i)*512 + k])
__global__ void tr_w_kernel(const float* __restrict__ W, short* __restrict__ WT) {
  __shared__ float Ws[64][65];
  int i0 = blockIdx.x * 64, k0 = blockIdx.y * 64, h = blockIdx.z;
  int tid = threadIdx.x;
  int r = tid >> 2, c0 = (tid & 3) * 16;
  const float* src = W + ((size_t)(h * 512 + i0 + r)) * 512 + k0 + c0;
  #pragma unroll
  for (int j = 0; j < 16; ++j) Ws[r][c0 + j] = src[j];
  __syncthreads();
  short* dst = WT + ((size_t)(h * 512 + k0 + r)) * 512 + i0 + c0;
  #pragma unroll
  for (int j = 0; j < 16; ++j) dst[j] = f2bs(Ws[c0 + j][r]);
}

// ===========================================================================
// weff128: Weff[(mat*CH+ch)*512+n][tap*512+k] = sum_i wpT[n][tap*512+i]*WT[h][k][i]
// grid (4, 4, 12*CH)
// ===========================================================================
__global__ void weff128(const short* __restrict__ wpqT, const short* __restrict__ wpkT,
                        const short* __restrict__ wpvT,
                        const short* __restrict__ WqT, const short* __restrict__ WkT,
                        const short* __restrict__ WvT,
                        int h0, int CH, short* __restrict__ Weff) {
  __shared__ __align__(16) short As[128 * BK];
  __shared__ __align__(16) short Bs[128 * BK];
  int n0 = blockIdx.x * 128, k0 = blockIdx.y * 128;
  int z = blockIdx.z;
  int mat = z / (4 * CH), rem = z % (4 * CH);
  int ch = rem >> 2, tap = rem & 3;
  const short* wpT = mat == 0 ? wpqT : (mat == 1 ? wpkT : wpvT);
  const short* WT  = mat == 0 ? WqT  : (mat == 1 ? WkT  : WvT);
  int h = h0 + ch;
  int tid = threadIdx.x, lane = tid & 63, w = tid >> 6, wr = w >> 1, wc = w & 1;
  int rbase = tid >> 3;
  int ss = ((tid & 7) ^ (rbase & 7)) << 3;   // pre-swizzled source slot (shorts)
  f32x4 acc[4][4] = {};
  for (int kq = 0; kq < 512; kq += BK) {
    #pragma unroll
    for (int p = 0; p < 4; ++p) {
      int row = rbase + 32 * p;
      short* dst = As + (32 * p + 8 * w) * BK;
      gload16(wpT + (size_t)(n0 + row) * 2048 + tap * 512 + kq + ss, dst);
      gload16(WT + ((size_t)(h * 512 + k0 + row)) * 512 + kq + ss,
              Bs + (32 * p + 8 * w) * BK);
    }
    __syncthreads();
    mma128(As, Bs, lane, wr, wc, acc);
    __syncthreads();
  }
  int m = lane & 15, quad = lane >> 4;
  size_t base = ((size_t)(mat * CH + ch) * 512) * 2048 + tap * 512;
  #pragma unroll
  for (int i = 0; i < 4; ++i)
    #pragma unroll
    for (int j = 0; j < 4; ++j)
      #pragma unroll
      for (int e = 0; e < 4; ++e) {
        int n = n0 + wr * 64 + i * 16 + quad * 4 + e;
        int k = k0 + wc * 64 + j * 16 + m;
        Weff[base + (size_t)n * 2048 + k] = f2bs(acc[i][j][e]);
      }
}

// beff_all[(mat*CH+ch)][n]
__global__ void beff_fused(const float* __restrict__ bq, const float* __restrict__ bk,
                           const float* __restrict__ bv,
                           const float* __restrict__ wpq, const float* __restrict__ wpk,
                           const float* __restrict__ wpv,
                           int h0, int CH, float* __restrict__ beff) {
  int mat = blockIdx.x, ch = blockIdx.y, tid = threadIdx.x;
  const float* bias = mat == 0 ? bq : (mat == 1 ? bk : bv);
  const float* wp = mat == 0 ? wpq : (mat == 1 ? wpk : wpv);
  for (int n = tid; n < 512; n += 256) {
    float s = 0.f;
    for (int i = 0; i < 512; ++i) {
      float bi = bias[(h0 + ch) * 512 + i];
      const float* w4 = wp + (size_t)n * 2048 + i * 4;
      s += bi * (w4[0] + w4[1] + w4[2] + w4[3]);
    }
    beff[(mat * CH + ch) * 512 + n] = s;
  }
}

// ===========================================================================
// pool128: flattened GEMM  M=(13 m-tiles x 2 b), Nflat=3*CH*512, K=2048.
// XCD swizzle clusters same-A blocks: v=ell&7 owns mb in [4v,4v+4).
// grid 1D: 8*4*(12*CH) blocks.
// ===========================================================================
__global__ void pool128(const short* __restrict__ xbf, const short* __restrict__ Weff,
                        const float* __restrict__ beff, const float* __restrict__ embz,
                        short* __restrict__ PQ, short* __restrict__ PKf,
                        short* __restrict__ PVt, int CH) {
  int ell = blockIdx.x;
  int v = ell & 7, u = ell >> 3;
  int NT = 12 * CH;
  int nt = u % NT, mbl = u / NT;
  int mb = v * 4 + mbl;
  if (mb >= 26) return;
  int mt = mb % 13, b = mb / 13;
  int mat = nt / (4 * CH), ch = (nt >> 2) % CH;
  int n0t = (nt & 3) * 128;
  int cg = b * CH + ch;

  __shared__ __align__(16) short As[128 * BK];
  __shared__ __align__(16) short Bs[128 * BK];
  int tid = threadIdx.x, lane = tid & 63, w = tid >> 6, wr = w >> 1, wc = w & 1;
  int rbase = tid >> 3;
  int ss = ((tid & 7) ^ (rbase & 7)) << 3;
  // prologue: pooled-position row bases for the 4 staged rows
  int l0r[4];
  #pragma unroll
  for (int p = 0; p < 4; ++p) {
    int row = rbase + 32 * p;
    int pb = mt * 128 + row; if (pb > Pp - 1) pb = Pp - 1;
    int t3 = pb / 196, rm = pb % 196, h2 = rm / 14, w2 = rm % 14;
    l0r[p] = 1 + t3 * 784 + h2 * 56 + w2 * 2;
  }
  const short* xb = xbf + (size_t)b * Ll * 512;
  const int taprow[4] = {0, 1, 28, 29};
  f32x4 acc[4][4] = {};
  for (int kq = 0; kq < 2048; kq += BK) {
    int tap = kq >> 9, koff = kq & 511;
    #pragma unroll
    for (int p = 0; p < 4; ++p) {
      int row = rbase + 32 * p;
      int lrow = l0r[p] + taprow[tap];
      gload16(xb + (size_t)lrow * 512 + koff + ss, As + (32 * p + 8 * w) * BK);
      gload16(Weff + ((size_t)nt * 128 + row) * 2048 + kq + ss,
              Bs + (32 * p + 8 * w) * BK);
    }
    __syncthreads();
    mma128(As, Bs, lane, wr, wc, acc);
    __syncthreads();
  }
  int m = lane & 15, quad = lane >> 4;
  #pragma unroll
  for (int i = 0; i < 4; ++i)
    #pragma unroll
    for (int j = 0; j < 4; ++j)
      #pragma unroll
      for (int e = 0; e < 4; ++e) {
        int row = wr * 64 + i * 16 + quad * 4 + e;
        int pb = mt * 128 + row;
        if (pb >= Pp) continue;
        int tok = pb + 1;
        int colLocal = wc * 64 + j * 16 + m;
        int n = n0t + colLocal;
        float val = acc[i][j][e] + beff[nt * 128 + colLocal];
        if (mat == 0)      PQ[((size_t)cg * LP + tok) * 512 + n] = f2bs(val);
        else if (mat == 1) PKf[((size_t)cg * LP + tok) * 512 + n] =
                               f2bs(val * QK_SCALE + embz[(size_t)tok * 512 + n]);
        else               PVt[((size_t)cg * 512 + n) * LP + tok] = f2bs(val);
      }
}

// PX pooled GEMM (64-tile; small)
__global__ void px_pool(const short* __restrict__ xbf, const short* __restrict__ wpxT,
                        short* __restrict__ PX) {
  __shared__ short As[64 * LDT];
  __shared__ short Bs[64 * LDT];
  int mt = blockIdx.x % 25, b = blockIdx.x / 25;
  int n0 = blockIdx.y * 64;
  int tid = threadIdx.x, lane = tid & 63, w = tid >> 6, wr = w >> 1, wc = w & 1;
  int sr = tid >> 2, sc = (tid & 3) * 8;
  int mloc = mt * 64 + sr;
  int pb = mloc < Pp ? mloc : (Pp - 1);
  int t3 = pb / 196, rm = pb % 196, h2 = rm / 14, w2 = rm % 14;
  int l0 = 1 + t3 * 784 + h2 * 56 + w2 * 2;
  const short* xb = xbf + (size_t)b * Ll * 512;
  f32x4 acc[2][2] = {};
  for (int kq = 0; kq < 2048; kq += 32) {
    int tap = kq >> 9;
    int lrow = l0 + (tap >> 1) * 28 + (tap & 1);
    *(short8*)(As + sr * LDT + sc) =
        *(const short8*)(xb + (size_t)lrow * 512 + (kq & 511) + sc);
    *(short8*)(Bs + sr * LDT + sc) =
        *(const short8*)(wpxT + (size_t)(n0 + sr) * 2048 + kq + sc);
    __syncthreads();
    mma_step(As, Bs, lane, wr, wc, acc[0][0], acc[0][1], acc[1][0], acc[1][1]);
    __syncthreads();
  }
  int m = lane & 15, quad = lane >> 4;
  #pragma unroll
  for (int ri = 0; ri < 2; ++ri)
    #pragma unroll
    for (int ci = 0; ci < 2; ++ci)
      #pragma unroll
      for (int e = 0; e < 4; ++e) {
        int mrow = mt * 64 + wr * 32 + ri * 16 + quad * 4 + e;
        int tok = mrow + 1; if (tok > LP - 1) tok = LP - 1;
        int n = n0 + wc * 32 + ci * 16 + m;
        PX[((size_t)b * LP + tok) * 512 + n] = f2bs(acc[ri][ci][e]);
      }
}

// cls row (token 0): one wave per output dot product. grid(128, 3, 2CH)
__global__ void cls_fast(const short* __restrict__ xbf,
                         const float* __restrict__ Wq, const float* __restrict__ bq,
                         const float* __restrict__ Wk, const float* __restrict__ bk,
                         const float* __restrict__ Wv, const float* __restrict__ bv,
                         int h0, int CH,
                         short* __restrict__ PQ, short* __restrict__ PKf,
                         short* __restrict__ PVt) {
  int cg = blockIdx.z, mat = blockIdx.y;
  int wv = threadIdx.x >> 6, lane = threadIdx.x & 63;
  int n = blockIdx.x * 4 + wv;
  int b = cg / CH, h = h0 + cg % CH;
  const float* W = mat == 0 ? Wq : (mat == 1 ? Wk : Wv);
  const float* bias = mat == 0 ? bq : (mat == 1 ? bk : bv);
  const short* xr = xbf + (size_t)b * Ll * 512;
  const float* wr = W + ((size_t)(h * 512 + n)) * 512;
  float s = 0.f;
  #pragma unroll
  for (int j = 0; j < 8; ++j) {
    int k = lane * 8 + j;
    s += bs2f(xr[k]) * wr[k];
  }
  #pragma unroll
  for (int off = 32; off; off >>= 1) s += __shfl_down(s, off, 64);
  if (lane == 0) {
    s += bias[h * 512 + n];
    if (mat == 0)      PQ[((size_t)cg * LP) * 512 + n] = f2bs(s);
    else if (mat == 1) PKf[((size_t)cg * LP) * 512 + n] = f2bs(s * QK_SCALE);
    else               PVt[((size_t)cg * 512 + n) * LP] = f2bs(s);
  }
}

// PX cls row
__global__ void pxcls_kernel(const float* __restrict__ x, short* __restrict__ PX) {
  int b = blockIdx.x, n = threadIdx.x;
  PX[(size_t)b * LP * 512 + n] = f2bs(x[(size_t)b * Ll * 512 + n]);
}

// cfx[cg][kt] = dot(PQ[cg,0,:], embz[kt,:])
__global__ void cfix_kernel(const short* __restrict__ PQ, const float* __restrict__ embz,
                            int a0, float* __restrict__ cfx) {
  int cg = a0 + blockIdx.y;
  int wv = threadIdx.x >> 6, lane = threadIdx.x & 63;
  int kt = blockIdx.x * 4 + wv;
  if (kt >= LP) return;
  int ktc = kt < LL2 ? kt : (LL2 - 1);
  const short* q0 = PQ + (size_t)cg * LP * 512;
  const float* e = embz + (size_t)ktc * 512;
  float s = 0.f;
  #pragma unroll
  for (int j = 0; j < 8; ++j) {
    int d = lane * 8 + j;
    s += bs2f(q0[d]) * e[d];
  }
  #pragma unroll
  for (int off = 32; off; off >>= 1) s += __shfl_down(s, off, 64);
  if (lane == 0) cfx[(size_t)cg * LP + kt] = s;
}

// ===========================================================================
// logits128: Lg[z][q][kt] = PQ[cg] . PKf[cg]; row0 -= cfx. grid (13,13,na)
// ===========================================================================
__global__ void logits128(const short* __restrict__ PQ, const short* __restrict__ PKf,
                          const float* __restrict__ cfx, int a0, float* __restrict__ Lg) {
  __shared__ __align__(16) short As[128 * BK];
  __shared__ __align__(16) short Bs[128 * BK];
  int q0 = blockIdx.x * 128, k0 = blockIdx.y * 128, z = blockIdx.z;
  int cg = a0 + z;
  int tid = threadIdx.x, lane = tid & 63, w = tid >> 6, wr = w >> 1, wc = w & 1;
  int rbase = tid >> 3;
  int ss = ((tid & 7) ^ (rbase & 7)) << 3;
  const short* Aq = PQ + (size_t)cg * LP * 512;
  const short* Bk = PKf + (size_t)cg * LP * 512;
  f32x4 acc[4][4] = {};
  for (int kq = 0; kq < 512; kq += BK) {
    #pragma unroll
    for (int p = 0; p < 4; ++p) {
      int row = rbase + 32 * p;
      int ar = q0 + row; if (ar > LL2 - 1) ar = LL2 - 1;
      int br = k0 + row; if (br > LL2 - 1) br = LL2 - 1;
      gload16(Aq + (size_t)ar * 512 + kq + ss, As + (32 * p + 8 * w) * BK);
      gload16(Bk + (size_t)br * 512 + kq + ss, Bs + (32 * p + 8 * w) * BK);
    }
    __syncthreads();
    mma128(As, Bs, lane, wr, wc, acc);
    __syncthreads();
  }
  int m = lane & 15, quad = lane >> 4;
  float* lg = Lg + (size_t)z * LP * LP;
  const float* cf = cfx + (size_t)cg * LP;
  #pragma unroll
  for (int i = 0; i < 4; ++i)
    #pragma unroll
    for (int j = 0; j < 4; ++j)
      #pragma unroll
      for (int e = 0; e < 4; ++e) {
        int q = q0 + wr * 64 + i * 16 + quad * 4 + e;
        int kt = k0 + wc * 64 + j * 16 + m;
        if (q >= LP || kt >= LP) continue;
        float val = acc[i][j][e];
        if (q == 0) val -= cf[kt];
        lg[(size_t)q * LP + kt] = val;
      }
}

// softmax row (f32) -> bf16 attn in place
__global__ void softmax_kernel(float* __restrict__ Lg) {
  int q = blockIdx.x, z = blockIdx.y;
  float* p = Lg + ((size_t)z * LP + q) * LP;
  __shared__ float buf[LP];
  __shared__ float red[256];
  int tid = threadIdx.x;
  float mx = -1e30f;
  for (int j = tid; j < LL2; j += 256) { float v = p[j]; buf[j] = v; mx = fmaxf(mx, v); }
  red[tid] = mx; __syncthreads();
  for (int s = 128; s; s >>= 1) { if (tid < s) red[tid] = fmaxf(red[tid], red[tid + s]); __syncthreads(); }
  mx = red[0]; __syncthreads();
  float sum = 0.f;
  for (int j = tid; j < LL2; j += 256) { float e = __expf(buf[j] - mx); buf[j] = e; sum += e; }
  red[tid] = sum; __syncthreads();
  for (int s = 128; s; s >>= 1) { if (tid < s) red[tid] += red[tid + s]; __syncthreads(); }
  float inv = 1.f / red[0];
  short* o = (short*)p;
  for (int j = tid; j < LL2; j += 256) o[j] = f2bs(buf[j] * inv);
  for (int j = LL2 + tid; j < LP; j += 256) o[j] = 0;
}

// ===========================================================================
// av128: Outb[gg][q][n] = attn @ PVt + (q==0?1:2)*PQ. grid (13,4,na)
// ===========================================================================
__global__ void av128(const float* __restrict__ Lg, const short* __restrict__ PVt,
                      const short* __restrict__ PQ, short* __restrict__ Outb,
                      int h0, int CH, int a0) {
  __shared__ __align__(16) short As[128 * BK];
  __shared__ __align__(16) short Bs[128 * BK];
  int q0 = blockIdx.x * 128, n0 = blockIdx.y * 128, z = blockIdx.z;
  int cg = a0 + z;
  int b = cg / CH, gg = b * 8 + h0 + cg % CH;
  int tid = threadIdx.x, lane = tid & 63, w = tid >> 6, wr = w >> 1, wc = w & 1;
  int rbase = tid >> 3;
  int ss = ((tid & 7) ^ (rbase & 7)) << 3;
  const short* Aat = (const short*)(Lg + (size_t)z * LP * LP);  // bf16 rows, stride 2*LP
  const short* Bv = PVt + (size_t)cg * 512 * LP;
  f32x4 acc[4][4] = {};
  for (int kq = 0; kq < LP; kq += BK) {
    #pragma unroll
    for (int p = 0; p < 4; ++p) {
      int row = rbase + 32 * p;
      int ar = q0 + row; if (ar > LP - 1) ar = LP - 1;
      gload16(Aat + (size_t)ar * (2 * LP) + kq + ss, As + (32 * p + 8 * w) * BK);
      gload16(Bv + (size_t)(n0 + row) * LP + kq + ss, Bs + (32 * p + 8 * w) * BK);
    }
    __syncthreads();
    mma128(As, Bs, lane, wr, wc, acc);
    __syncthreads();
  }
  int m = lane & 15, quad = lane >> 4;
  #pragma unroll
  for (int i = 0; i < 4; ++i)
    #pragma unroll
    for (int j = 0; j < 4; ++j)
      #pragma unroll
      for (int e = 0; e < 4; ++e) {
        int q = q0 + wr * 64 + i * 16 + quad * 4 + e;
        if (q >= LL2) continue;
        int n = n0 + wc * 64 + j * 16 + m;
        float res = bs2f(PQ[((size_t)cg * LP + q) * 512 + n]);
        float val = acc[i][j][e] + (q == 0 ? 1.f : 2.f) * res;
        Outb[((size_t)gg * LP + q) * 512 + n] = f2bs(val);
      }
}

// ===========================================================================
// final128: Y = stacked @ Wd^T + bd + PX. grid (25, 4). M=3138 flat (b,q).
// ===========================================================================
__global__ void final128(const short* __restrict__ Outb, const short* __restrict__ WdB,
                         const float* __restrict__ bd, const short* __restrict__ PX,
                         float* __restrict__ Y) {
  __shared__ __align__(16) short As[128 * BK];
  __shared__ __align__(16) short Bs[128 * BK];
  int mf0 = blockIdx.x * 128, n0 = blockIdx.y * 128;
  int tid = threadIdx.x, lane = tid & 63, w = tid >> 6, wr = w >> 1, wc = w & 1;
  int rbase = tid >> 3;
  int ss = ((tid & 7) ^ (rbase & 7)) << 3;
  const int M = Bb * LL2;  // 3138
  int brow[4], qrow[4];
  #pragma unroll
  for (int p = 0; p < 4; ++p) {
    int mf = mf0 + rbase + 32 * p; if (mf > M - 1) mf = M - 1;
    brow[p] = mf / LL2; qrow[p] = mf % LL2;
  }
  f32x4 acc[4][4] = {};
  for (int kq = 0; kq < 4096; kq += BK) {
    int hh = kq >> 9, koff = kq & 511;
    #pragma unroll
    for (int p = 0; p < 4; ++p) {
      int row = rbase + 32 * p;
      gload16(Outb + ((size_t)(brow[p] * 8 + hh) * LP + qrow[p]) * 512 + koff + ss,
              As + (32 * p + 8 * w) * BK);
      gload16(WdB + (size_t)(n0 + row) * 4096 + kq + ss,
              Bs + (32 * p + 8 * w) * BK);
    }
    __syncthreads();
    mma128(As, Bs, lane, wr, wc, acc);
    __syncthreads();
  }
  int m = lane & 15, quad = lane >> 4;
  #pragma unroll
  for (int i = 0; i < 4; ++i)
    #pragma unroll
    for (int j = 0; j < 4; ++j)
      #pragma unroll
      for (int e = 0; e < 4; ++e) {
        int mf = mf0 + wr * 64 + i * 16 + quad * 4 + e;
        if (mf >= M) continue;
        int b2 = mf / LL2, q2 = mf % LL2;
        int dm = n0 + wc * 64 + j * 16 + m;
        float val = acc[i][j][e] + bd[dm] + bs2f(PX[((size_t)b2 * LP + q2) * 512 + dm]);
        Y[(size_t)mf * 512 + dm] = val;
      }
}

// LayerNorm over 512
__global__ void ln_kernel(const float* __restrict__ Y, const float* __restrict__ gamma,
                          const float* __restrict__ beta, float* __restrict__ Outp) {
  int row = blockIdx.x;
  const float* y = Y + (size_t)row * 512;
  __shared__ float red[256];
  int tid = threadIdx.x;
  float v0 = y[tid], v1 = y[tid + 256];
  red[tid] = v0 + v1; __syncthreads();
  for (int s = 128; s; s >>= 1) { if (tid < s) red[tid] += red[tid + s]; __syncthreads(); }
  float mu = red[0] * (1.f / 512.f);
  __syncthreads();
  float d0 = v0 - mu, d1 = v1 - mu;
  red[tid] = d0 * d0 + d1 * d1; __syncthreads();
  for (int s = 128; s; s >>= 1) { if (tid < s) red[tid] += red[tid + s]; __syncthreads(); }
  float rstd = rsqrtf(red[0] * (1.f / 512.f) + 1e-5f);
  float* o = Outp + (size_t)row * 512;
  o[tid]       = d0 * rstd * gamma[tid]       + beta[tid];
  o[tid + 256] = d1 * rstd * gamma[tid + 256] + beta[tid + 256];
}

// ---------------------------------------------------------------------------
extern "C" void kernel_launch(void* const* d_in, const int* in_sizes, int n_in,
                              void* d_out, int out_size, void* d_ws, size_t ws_size,
                              hipStream_t stream) {
  const float* x     = (const float*)d_in[0];
  const float* Wq    = (const float*)d_in[1];
  const float* bq    = (const float*)d_in[2];
  const float* Wk    = (const float*)d_in[3];
  const float* bk    = (const float*)d_in[4];
  const float* Wv    = (const float*)d_in[5];
  const float* bv    = (const float*)d_in[6];
  const float* wpq   = (const float*)d_in[7];
  const float* wpk   = (const float*)d_in[8];
  const float* wpv   = (const float*)d_in[9];
  const float* wpx   = (const float*)d_in[10];
  const float* Wd    = (const float*)d_in[11];
  const float* bd    = (const float*)d_in[12];
  const float* gamma = (const float*)d_in[13];
  const float* beta  = (const float*)d_in[14];
  float* outp = (float*)d_out;

  auto rnd = [](size_t b) { return (b + 255) / 256 * 256; };
  const size_t persist =
      rnd((size_t)LP * 512 * 4) +            // embz
      rnd((size_t)Bb * Ll * 512 * 2) +       // xbf
      4 * rnd((size_t)512 * 2048 * 2) +      // wpxT + wpqT/wpkT/wpvT
      3 * rnd((size_t)8 * 512 * 512 * 2) +   // WqT/WkT/WvT
      rnd((size_t)512 * 4096 * 2) +          // WdB
      rnd((size_t)16 * LP * 512 * 2) +       // Outb
      rnd((size_t)2 * LP * 512 * 2) +        // PX
      rnd((size_t)2 * LL2 * 512 * 4) +       // Y
      rnd((size_t)16 * LP * 4);              // cfx
  auto chpart = [&](int CH) {
    return rnd((size_t)3 * CH * 512 * 2048 * 2) + rnd((size_t)3 * CH * 512 * 4) +
           3 * rnd((size_t)2 * CH * LP * 512 * 2);
  };
  const size_t lgbytes = rnd((size_t)LP * LP * 4);
  int CH = 8;
  while (CH > 1 && persist + chpart(CH) + lgbytes > ws_size) CH >>= 1;
  if (persist + chpart(CH) + lgbytes > ws_size) return;
  int NA = (int)((ws_size - persist - chpart(CH)) / lgbytes);
  if (NA > 2 * CH) NA = 2 * CH;
  int nc = 8 / CH;

  char* w = (char*)d_ws;
  auto alloc = [&](size_t bytes) { char* p = w; w += (bytes + 255) / 256 * 256; return p; };
  float* embz = (float*)alloc((size_t)LP * 512 * 4);
  short* xbf  = (short*)alloc((size_t)Bb * Ll * 512 * 2);
  short* wpxT = (short*)alloc((size_t)512 * 2048 * 2);
  short* wpqT = (short*)alloc((size_t)512 * 2048 * 2);
  short* wpkT = (short*)alloc((size_t)512 * 2048 * 2);
  short* wpvT = (short*)alloc((size_t)512 * 2048 * 2);
  short* WqT  = (short*)alloc((size_t)8 * 512 * 512 * 2);
  short* WkT  = (short*)alloc((size_t)8 * 512 * 512 * 2);
  short* WvT  = (short*)alloc((size_t)8 * 512 * 512 * 2);
  short* WdB  = (short*)alloc((size_t)512 * 4096 * 2);
  short* Outb = (short*)alloc((size_t)16 * LP * 512 * 2);
  short* PX   = (short*)alloc((size_t)2 * LP * 512 * 2);
  float* Y    = (float*)alloc((size_t)2 * LL2 * 512 * 4);
  float* cfx  = (float*)alloc((size_t)16 * LP * 4);
  short* Weff = (short*)alloc((size_t)3 * CH * 512 * 2048 * 2);
  float* beff = (float*)alloc((size_t)3 * CH * 512 * 4);
  short* PQ   = (short*)alloc((size_t)2 * CH * LP * 512 * 2);
  short* PKf  = (short*)alloc((size_t)2 * CH * LP * 512 * 2);
  short* PVt  = (short*)alloc((size_t)2 * CH * LP * 512 * 2);
  float* Lg   = (float*)alloc((size_t)NA * LP * LP * 4);

  dim3 blk(256);
  emb_kernel<<<dim3((LP * 512 + 255) / 256), blk, 0, stream>>>(embz);
  cvt_kernel<<<dim3((Bb * Ll * 512 / 4 + 255) / 256), blk, 0, stream>>>(x, xbf, Bb * Ll * 512 / 4);
  wpxt_kernel<<<dim3(4096), blk, 0, stream>>>(wpx, wpxT);
  wpxt_kernel<<<dim3(4096), blk, 0, stream>>>(wpq, wpqT);
  wpxt_kernel<<<dim3(4096), blk, 0, stream>>>(wpk, wpkT);
  wpxt_kernel<<<dim3(4096), blk, 0, stream>>>(wpv, wpvT);
  tr_w_kernel<<<dim3(8, 8, 8), blk, 0, stream>>>(Wq, WqT);
  tr_w_kernel<<<dim3(8, 8, 8), blk, 0, stream>>>(Wk, WkT);
  tr_w_kernel<<<dim3(8, 8, 8), blk, 0, stream>>>(Wv, WvT);
  cvt_kernel<<<dim3((512 * 4096 / 4 + 255) / 256), blk, 0, stream>>>(Wd, WdB, 512 * 4096 / 4);
  px_pool<<<dim3(50, 8), blk, 0, stream>>>(xbf, wpxT, PX);
  pxcls_kernel<<<dim3(2), dim3(512), 0, stream>>>(x, PX);

  for (int c = 0; c < nc; ++c) {
    int h0 = c * CH;
    weff128<<<dim3(4, 4, 12 * CH), blk, 0, stream>>>(wpqT, wpkT, wpvT, WqT, WkT, WvT,
                                                     h0, CH, Weff);
    beff_fused<<<dim3(3, CH), blk, 0, stream>>>(bq, bk, bv, wpq, wpk, wpv, h0, CH, beff);
    pool128<<<dim3(8 * 4 * 12 * CH), blk, 0, stream>>>(xbf, Weff, beff, embz,
                                                       PQ, PKf, PVt, CH);
    cls_fast<<<dim3(128, 3, 2 * CH), blk, 0, stream>>>(xbf, Wq, bq, Wk, bk, Wv, bv,
                                                       h0, CH, PQ, PKf, PVt);
    for (int a0 = 0; a0 < 2 * CH; a0 += NA) {
      int na = (2 * CH - a0) < NA ? (2 * CH - a0) : NA;
      cfix_kernel<<<dim3(400, na), blk, 0, stream>>>(PQ, embz, a0, cfx);
      logits128<<<dim3(13, 13, na), blk, 0, stream>>>(PQ, PKf, cfx, a0, Lg);
      softmax_kernel<<<dim3(LL2, na), blk, 0, stream>>>(Lg);
      av128<<<dim3(13, 4, na), blk, 0, stream>>>(Lg, PVt, PQ, Outb, h0, CH, a0);
    }
  }

  final128<<<dim3(25, 4), blk, 0, stream>>>(Outb, WdB, bd, PX, Y);
  ln_kernel<<<dim3(Bb * LL2), blk, 0, stream>>>(Y, gamma, beta, outp);
}